// Round 5
// baseline (287.518 us; speedup 1.0000x reference)
//
#include <hip/hip_runtime.h>

// Problem constants
#define Bn 2
#define Tdim 2048
#define Ddim 1024
#define Hn 16
#define HD 64

typedef unsigned short u16;
typedef unsigned int u32;
typedef __attribute__((ext_vector_type(8))) __bf16 bf16x8;
typedef __attribute__((ext_vector_type(4))) float f32x4;

struct alignas(8) U16x4 { u16 x, y, z, w; };

__device__ __forceinline__ u16 f2bf(float f) {
  union { float f; u32 i; } v; v.f = f;
  u32 x = v.i;
  u32 r = (x + 0x7fffu + ((x >> 16) & 1u)) >> 16;
  return (u16)r;
}

__device__ __forceinline__ f32x4 mfma16(bf16x8 a, bf16x8 b, f32x4 c) {
  return __builtin_amdgcn_mfma_f32_16x16x32_bf16(a, b, c, 0, 0, 0);
}

// ---------------- X f32 -> bf16 convert ----------------
__global__ __launch_bounds__(256) void convert_x(const float* __restrict__ src,
                                                 u16* __restrict__ dst) {
  const int i = (blockIdx.x * 256 + threadIdx.x) * 8;
  u16 t[8];
#pragma unroll
  for (int j = 0; j < 8; j++) t[j] = f2bf(src[i + j]);
  *(bf16x8*)&dst[i] = *(const bf16x8*)t;
}

// ---------------- weight transpose + f32->bf16 convert (1024x1024) ----------------
__global__ __launch_bounds__(256) void transpose_k(const float* __restrict__ src,
                                                   u16* __restrict__ dst) {
  __shared__ u16 tile[32][33];
  const int tx = threadIdx.x, ty = threadIdx.y;
  const int x = blockIdx.x * 32 + tx;
  const int y0 = blockIdx.y * 32;
#pragma unroll
  for (int j = 0; j < 32; j += 8) tile[ty + j][tx] = f2bf(src[(size_t)(y0 + ty + j) * Ddim + x]);
  __syncthreads();
  const int xo = blockIdx.y * 32 + tx;
  const int yo0 = blockIdx.x * 32;
#pragma unroll
  for (int j = 0; j < 32; j += 8) dst[(size_t)(yo0 + ty + j) * Ddim + xo] = tile[tx][ty + j];
}

// ---------------- fused QKV projection GEMM ----------------
// C(4096x1024) = Xb(4096x1024 bf16) * W (via pre-transposed bf16 Wt)
// z=0 -> Q (B,H,T,64) bf16; z=1 -> K bf16; z=2 -> V stored transposed (B,H,64,T) bf16
__global__ __launch_bounds__(256, 2) void gemm_qkv(
    const u16* __restrict__ Xb,
    const u16* __restrict__ WqT, const u16* __restrict__ WkT, const u16* __restrict__ WvT,
    const float* __restrict__ bq, const float* __restrict__ bk, const float* __restrict__ bv,
    u16* __restrict__ Q, u16* __restrict__ K, u16* __restrict__ Vt) {
  const int z = blockIdx.z;
  const u16* Wt = (z == 0) ? WqT : (z == 1) ? WkT : WvT;
  const float* bias = (z == 0) ? bq : (z == 1) ? bk : bv;
  u16* QK = (z == 0) ? Q : K;

  __shared__ alignas(16) u16 Alds[128 * 32];
  __shared__ alignas(16) u16 Blds[128 * 32];
  const int tid = threadIdx.x;
  const int w = tid >> 6, lane = tid & 63, ln = lane & 15, quad = lane >> 4;
  const int wm = (w >> 1) * 64, wn = (w & 1) * 64;
  const int tm = blockIdx.x * 128, tn = blockIdx.y * 128;

  f32x4 acc[4][4] = {};

  for (int k0 = 0; k0 < Ddim; k0 += 32) {
    __syncthreads();
    // staging: flat element e = rho*2048 + tid*8; row=e>>5, col=e&31
#pragma unroll
    for (int rho = 0; rho < 2; rho++) {
      const int e = rho * 2048 + tid * 8;
      const int row = e >> 5, col = e & 31;
      *(bf16x8*)&Alds[e] = *(const bf16x8*)&Xb[(size_t)(tm + row) * Ddim + k0 + col];
      *(bf16x8*)&Blds[e] = *(const bf16x8*)&Wt[(size_t)(tn + row) * Ddim + k0 + col];
    }
    __syncthreads();
    bf16x8 af[4], bfr[4];
#pragma unroll
    for (int i = 0; i < 4; i++)
      af[i] = *(const bf16x8*)&Alds[(wm + i * 16 + ln) * 32 + quad * 8];
#pragma unroll
    for (int i = 0; i < 4; i++)
      bfr[i] = *(const bf16x8*)&Blds[(wn + i * 16 + ln) * 32 + quad * 8];
#pragma unroll
    for (int mi = 0; mi < 4; mi++)
#pragma unroll
      for (int ni = 0; ni < 4; ni++)
        acc[mi][ni] = mfma16(af[mi], bfr[ni], acc[mi][ni]);
  }

#pragma unroll
  for (int mi = 0; mi < 4; mi++) {
#pragma unroll
    for (int ni = 0; ni < 4; ni++) {
      const int gm0 = tm + wm + mi * 16 + quad * 4;  // 4 consecutive rows (reg axis)
      const int gn = tn + wn + ni * 16 + ln;
      const float bv_ = bias[gn];
      const int hh = gn >> 6, dd = gn & 63;
      const int b0 = gm0 >> 11, t0 = gm0 & 2047;
      if (z < 2) {
        u16* p = QK + (((size_t)(b0 * Hn + hh) * Tdim) + t0) * HD + dd;
#pragma unroll
        for (int r = 0; r < 4; r++) p[r * HD] = f2bf(acc[mi][ni][r] + bv_);
      } else {
        U16x4 pk;
        pk.x = f2bf(acc[mi][ni][0] + bv_);
        pk.y = f2bf(acc[mi][ni][1] + bv_);
        pk.z = f2bf(acc[mi][ni][2] + bv_);
        pk.w = f2bf(acc[mi][ni][3] + bv_);
        *(U16x4*)&Vt[((size_t)(b0 * Hn + hh) * HD + dd) * Tdim + t0] = pk;
      }
    }
  }
}

// ---------------- flash attention v2 (causal + ALiBi) ----------------
// grid: (T/64, B*H); block 256 (4 waves). Each wave owns 16 q-rows.
// LDS padded strides: K rows 72, V^T rows 136 -> ds_read_b128 at bank floor.
#define KSTR 72
#define VSTR 136
__global__ __launch_bounds__(256, 3) void attn_k(
    const u16* __restrict__ Q, const u16* __restrict__ K, const u16* __restrict__ Vt,
    u16* __restrict__ O) {
  __shared__ alignas(16) u16 Klds[128 * KSTR];   // 18432 B
  __shared__ alignas(16) u16 Vtlds[64 * VSTR];   // 17408 B
  __shared__ alignas(16) u16 Pq[8704];           // 17408 B: Q stage (64x72), then P (4w x 16 x 136)

  const int qt = blockIdx.x, bh = blockIdx.y;
  const int b = bh >> 4, h = bh & 15;
  const int q0 = qt * 64;
  const int tid = threadIdx.x;
  const int w = tid >> 6, lane = tid & 63, ln = lane & 15, quad = lane >> 4;

  const u16* Qh = Q + (size_t)bh * Tdim * HD;
  const u16* Kh = K + (size_t)bh * Tdim * HD;
  const u16* Vh = Vt + (size_t)bh * HD * Tdim;
  const float slope = exp2f(-0.5f * (float)(h + 1));

  // stage Q tile (64x64) at stride 72
#pragma unroll
  for (int c = 0; c < 2; c++) {
    const int e = c * 2048 + tid * 8;
    const int row = e >> 6, col = e & 63;
    *(bf16x8*)&Pq[row * KSTR + col] = *(const bf16x8*)&Qh[(size_t)(q0 + row) * HD + col];
  }
  __syncthreads();

  bf16x8 qf[2];
#pragma unroll
  for (int ks = 0; ks < 2; ks++)
    qf[ks] = *(const bf16x8*)&Pq[(w * 16 + ln) * KSTR + ks * 32 + quad * 8];

  float mst[4], lst[4];
#pragma unroll
  for (int r = 0; r < 4; r++) { mst[r] = -INFINITY; lst[r] = 0.f; }
  f32x4 oacc[4] = {};

  u16* Pw = &Pq[w * 16 * VSTR];  // this wave's P region: 16 x 128 (stride 136)
  const int nkt = (qt >> 1) + 1;

  for (int kt = 0; kt < nkt; kt++) {
    const int kb = kt * 128;
    __syncthreads();  // previous iteration's K/V reads done
#pragma unroll
    for (int c = 0; c < 4; c++) {
      const int e = c * 2048 + tid * 8;
      const int kr = e >> 6, kc = e & 63;        // K tile: 128 keys x 64
      bf16x8 vk = *(const bf16x8*)&Kh[(size_t)(kb + kr) * HD + kc];
      const int vr = e >> 7, vc = e & 127;       // V^T tile: 64 d x 128 keys
      bf16x8 vv = *(const bf16x8*)&Vh[(size_t)vr * Tdim + kb + vc];
      *(bf16x8*)&Klds[kr * KSTR + kc] = vk;
      *(bf16x8*)&Vtlds[vr * VSTR + vc] = vv;
    }
    __syncthreads();  // staging visible

    // S = Q K^T   (wave: 16q x 128k)
    f32x4 s[8] = {};
#pragma unroll
    for (int ks = 0; ks < 2; ks++) {
#pragma unroll
      for (int ni = 0; ni < 8; ni++) {
        bf16x8 kf = *(const bf16x8*)&Klds[(ni * 16 + ln) * KSTR + ks * 32 + quad * 8];
        s[ni] = mfma16(qf[ks], kf, s[ni]);
      }
    }

    // scale + ALiBi + causal mask, row max
    float rmax[4];
#pragma unroll
    for (int r = 0; r < 4; r++) rmax[r] = -INFINITY;
    const bool diag = (kt == nkt - 1);
#pragma unroll
    for (int ni = 0; ni < 8; ni++) {
      const int n = kb + ni * 16 + ln;
      const float ab = -slope * (float)(Tdim - 1 - n);
#pragma unroll
      for (int r = 0; r < 4; r++) {
        float sv = s[ni][r] * 0.125f + ab;
        if (diag) {
          const int qg = q0 + w * 16 + quad * 4 + r;
          if (n > qg) sv = -1e30f;
        }
        s[ni][r] = sv;
        rmax[r] = fmaxf(rmax[r], sv);
      }
    }
#pragma unroll
    for (int r = 0; r < 4; r++) {
#pragma unroll
      for (int off = 8; off >= 1; off >>= 1)
        rmax[r] = fmaxf(rmax[r], __shfl_xor(rmax[r], off));
    }

    float alpha[4];
#pragma unroll
    for (int r = 0; r < 4; r++) {
      const float mn = fmaxf(mst[r], rmax[r]);
      alpha[r] = __expf(mst[r] - mn);
      mst[r] = mn;
    }

    float rsum[4] = {};
#pragma unroll
    for (int ni = 0; ni < 8; ni++) {
#pragma unroll
      for (int r = 0; r < 4; r++) {
        const float p = __expf(s[ni][r] - mst[r]);
        rsum[r] += p;
        Pw[(quad * 4 + r) * VSTR + ni * 16 + ln] = f2bf(p);
      }
    }
#pragma unroll
    for (int r = 0; r < 4; r++) {
#pragma unroll
      for (int off = 8; off >= 1; off >>= 1)
        rsum[r] += __shfl_xor(rsum[r], off);
      lst[r] = lst[r] * alpha[r] + rsum[r];
    }
#pragma unroll
    for (int nd = 0; nd < 4; nd++)
#pragma unroll
      for (int r = 0; r < 4; r++) oacc[nd][r] *= alpha[r];

    // P is wave-private: no barrier needed (compiler inserts lgkmcnt waits)

    // O += P * V   (P: A-layout from LDS; V^T rows as B operand)
#pragma unroll
    for (int ks = 0; ks < 4; ks++) {
      bf16x8 pf = *(const bf16x8*)&Pw[ln * VSTR + ks * 32 + quad * 8];
#pragma unroll
      for (int nd = 0; nd < 4; nd++) {
        bf16x8 vf = *(const bf16x8*)&Vtlds[(nd * 16 + ln) * VSTR + ks * 32 + quad * 8];
        oacc[nd] = mfma16(pf, vf, oacc[nd]);
      }
    }
  }

  // epilogue: write (b, t, h*64+d) bf16 intermediate
#pragma unroll
  for (int nd = 0; nd < 4; nd++) {
    const int d = nd * 16 + ln;
#pragma unroll
    for (int r = 0; r < 4; r++) {
      const int t = q0 + w * 16 + quad * 4 + r;
      O[((size_t)(b * Tdim + t)) * Ddim + h * HD + d] = f2bf(oacc[nd][r] / lst[r]);
    }
  }
}

// ---------------- output projection GEMM (bf16 x bf16 -> f32 out) ----------------
__global__ __launch_bounds__(256, 2) void gemm_out(
    const u16* __restrict__ A, const u16* __restrict__ WoT, const float* __restrict__ bo,
    float* __restrict__ C) {
  __shared__ alignas(16) u16 Alds[128 * 32];
  __shared__ alignas(16) u16 Blds[128 * 32];
  const int tid = threadIdx.x;
  const int w = tid >> 6, lane = tid & 63, ln = lane & 15, quad = lane >> 4;
  const int wm = (w >> 1) * 64, wn = (w & 1) * 64;
  const int tm = blockIdx.x * 128, tn = blockIdx.y * 128;

  f32x4 acc[4][4] = {};

  for (int k0 = 0; k0 < Ddim; k0 += 32) {
    __syncthreads();
#pragma unroll
    for (int rho = 0; rho < 2; rho++) {
      const int e = rho * 2048 + tid * 8;
      const int row = e >> 5, col = e & 31;
      bf16x8 va = *(const bf16x8*)&A[(size_t)(tm + row) * Ddim + k0 + col];
      bf16x8 vb = *(const bf16x8*)&WoT[(size_t)(tn + row) * Ddim + k0 + col];
      *(bf16x8*)&Alds[e] = va;
      *(bf16x8*)&Blds[e] = vb;
    }
    __syncthreads();
    bf16x8 af[4], bfr[4];
#pragma unroll
    for (int i = 0; i < 4; i++)
      af[i] = *(const bf16x8*)&Alds[(wm + i * 16 + ln) * 32 + quad * 8];
#pragma unroll
    for (int i = 0; i < 4; i++)
      bfr[i] = *(const bf16x8*)&Blds[(wn + i * 16 + ln) * 32 + quad * 8];
#pragma unroll
    for (int mi = 0; mi < 4; mi++)
#pragma unroll
      for (int ni = 0; ni < 4; ni++)
        acc[mi][ni] = mfma16(af[mi], bfr[ni], acc[mi][ni]);
  }

#pragma unroll
  for (int mi = 0; mi < 4; mi++) {
#pragma unroll
    for (int ni = 0; ni < 4; ni++) {
      const int gm0 = tm + wm + mi * 16 + quad * 4;
      const int gn = tn + wn + ni * 16 + ln;
      const float bv_ = bo[gn];
#pragma unroll
      for (int r = 0; r < 4; r++)
        C[(size_t)(gm0 + r) * Ddim + gn] = acc[mi][ni][r] + bv_;
    }
  }
}

extern "C" void kernel_launch(void* const* d_in, const int* in_sizes, int n_in,
                              void* d_out, int out_size, void* d_ws, size_t ws_size,
                              hipStream_t stream) {
  (void)in_sizes; (void)n_in; (void)out_size; (void)ws_size;
  const float* x  = (const float*)d_in[0];
  const float* Wq = (const float*)d_in[1];
  const float* bq = (const float*)d_in[2];
  const float* Wk = (const float*)d_in[3];
  const float* bk = (const float*)d_in[4];
  const float* Wv = (const float*)d_in[5];
  const float* bv = (const float*)d_in[6];
  const float* Wo = (const float*)d_in[7];
  const float* bo = (const float*)d_in[8];

  char* ws = (char*)d_ws;
  const size_t MB = 1024 * 1024;
  u16* WqT = (u16*)(ws + 0 * MB);   // 2MB bf16 1024x1024
  u16* WkT = (u16*)(ws + 2 * MB);
  u16* WvT = (u16*)(ws + 4 * MB);
  u16* WoT = (u16*)(ws + 6 * MB);
  u16* Qb  = (u16*)(ws + 8 * MB);   // 8MB bf16 (B,H,T,64)
  u16* Kb  = (u16*)(ws + 16 * MB);
  u16* Vtb = (u16*)(ws + 24 * MB);  // 8MB bf16 (B,H,64,T)
  u16* Xb  = (u16*)(ws + 32 * MB);  // 8MB bf16 X; overlaps AO (AO written after Xb consumed)
  u16* AO  = (u16*)(ws + 32 * MB);  // 8MB bf16 (B,T,D)

  convert_x<<<dim3(2048), 256, 0, stream>>>(x, Xb);
  dim3 tb(32, 8);
  transpose_k<<<dim3(32, 32), tb, 0, stream>>>(Wq, WqT);
  transpose_k<<<dim3(32, 32), tb, 0, stream>>>(Wk, WkT);
  transpose_k<<<dim3(32, 32), tb, 0, stream>>>(Wv, WvT);
  transpose_k<<<dim3(32, 32), tb, 0, stream>>>(Wo, WoT);

  gemm_qkv<<<dim3(32, 8, 3), 256, 0, stream>>>(Xb, WqT, WkT, WvT, bq, bk, bv, Qb, Kb, Vtb);
  attn_k<<<dim3(32, 32), 256, 0, stream>>>(Qb, Kb, Vtb, AO);
  gemm_out<<<dim3(32, 8), 256, 0, stream>>>(AO, WoT, bo, (float*)d_out);
}

// Round 6
// 254.282 us; speedup vs baseline: 1.1307x; 1.1307x over previous
//
#include <hip/hip_runtime.h>

// Problem constants
#define Bn 2
#define Tdim 2048
#define Ddim 1024
#define Hn 16
#define HD 64

typedef unsigned short u16;
typedef unsigned int u32;
typedef __attribute__((ext_vector_type(8))) __bf16 bf16x8;
typedef __attribute__((ext_vector_type(4))) float f32x4;

struct alignas(8) U16x4 { u16 x, y, z, w; };

__device__ __forceinline__ u16 f2bf(float f) {
  union { float f; u32 i; } v; v.f = f;
  u32 x = v.i;
  u32 r = (x + 0x7fffu + ((x >> 16) & 1u)) >> 16;
  return (u16)r;
}

// async global->LDS, 16B per lane; LDS dest = wave-uniform base + lane*16
__device__ __forceinline__ void cp16(const u16* g, u16* l) {
  __builtin_amdgcn_global_load_lds(
      (const __attribute__((address_space(1))) u32*)g,
      (__attribute__((address_space(3))) u32*)l, 16, 0, 0);
}

__device__ __forceinline__ f32x4 mfma16(bf16x8 a, bf16x8 b, f32x4 c) {
  return __builtin_amdgcn_mfma_f32_16x16x32_bf16(a, b, c, 0, 0, 0);
}

// ---------------- X f32 -> bf16 convert ----------------
__global__ __launch_bounds__(256) void convert_x(const float* __restrict__ src,
                                                 u16* __restrict__ dst) {
  const int i = (blockIdx.x * 256 + threadIdx.x) * 8;
  u16 t[8];
#pragma unroll
  for (int j = 0; j < 8; j++) t[j] = f2bf(src[i + j]);
  *(bf16x8*)&dst[i] = *(const bf16x8*)t;
}

// ---------------- weight transpose + f32->bf16 convert (1024x1024) ----------------
__global__ __launch_bounds__(256) void transpose_k(const float* __restrict__ src,
                                                   u16* __restrict__ dst) {
  __shared__ u16 tile[32][33];
  const int tx = threadIdx.x, ty = threadIdx.y;
  const int x = blockIdx.x * 32 + tx;
  const int y0 = blockIdx.y * 32;
#pragma unroll
  for (int j = 0; j < 32; j += 8) tile[ty + j][tx] = f2bf(src[(size_t)(y0 + ty + j) * Ddim + x]);
  __syncthreads();
  const int xo = blockIdx.y * 32 + tx;
  const int yo0 = blockIdx.x * 32;
#pragma unroll
  for (int j = 0; j < 32; j += 8) dst[(size_t)(yo0 + ty + j) * Ddim + xo] = tile[tx][ty + j];
}

// ---------------- fused QKV projection GEMM (global_load_lds staging) ----------------
// z=0 -> Q (B,H,T,64) bf16; z=1 -> K bf16; z=2 -> V stored transposed (B,H,64,T) bf16
__global__ __launch_bounds__(256, 2) void gemm_qkv(
    const u16* __restrict__ Xb,
    const u16* __restrict__ WqT, const u16* __restrict__ WkT, const u16* __restrict__ WvT,
    const float* __restrict__ bq, const float* __restrict__ bk, const float* __restrict__ bv,
    u16* __restrict__ Q, u16* __restrict__ K, u16* __restrict__ Vt) {
  const int z = blockIdx.z;
  const u16* Wt = (z == 0) ? WqT : (z == 1) ? WkT : WvT;
  const float* bias = (z == 0) ? bq : (z == 1) ? bk : bv;
  u16* QK = (z == 0) ? Q : K;

  __shared__ alignas(16) u16 Alds[128 * 32];
  __shared__ alignas(16) u16 Blds[128 * 32];
  const int tid = threadIdx.x;
  const int w = tid >> 6, lane = tid & 63, ln = lane & 15, quad = lane >> 4;
  const int wm = (w >> 1) * 64, wn = (w & 1) * 64;
  const int tm = blockIdx.x * 128, tn = blockIdx.y * 128;

  f32x4 acc[4][4] = {};

  const int srow = tid >> 2, scol = (tid & 3) * 8;
  const u16* ag = Xb + (size_t)(tm + srow) * Ddim + scol;
  const u16* ag2 = ag + (size_t)64 * Ddim;
  const u16* bg = Wt + (size_t)(tn + srow) * Ddim + scol;
  const u16* bg2 = bg + (size_t)64 * Ddim;
  u16* al = &Alds[w * 512];
  u16* al2 = &Alds[2048 + w * 512];
  u16* bl = &Blds[w * 512];
  u16* bl2 = &Blds[2048 + w * 512];

  for (int k0 = 0; k0 < Ddim; k0 += 32) {
    __syncthreads();
    cp16(ag + k0, al);
    cp16(ag2 + k0, al2);
    cp16(bg + k0, bl);
    cp16(bg2 + k0, bl2);
    __syncthreads();
    bf16x8 af[4], bfr[4];
#pragma unroll
    for (int i = 0; i < 4; i++)
      af[i] = *(const bf16x8*)&Alds[(wm + i * 16 + ln) * 32 + quad * 8];
#pragma unroll
    for (int i = 0; i < 4; i++)
      bfr[i] = *(const bf16x8*)&Blds[(wn + i * 16 + ln) * 32 + quad * 8];
#pragma unroll
    for (int mi = 0; mi < 4; mi++)
#pragma unroll
      for (int ni = 0; ni < 4; ni++)
        acc[mi][ni] = mfma16(af[mi], bfr[ni], acc[mi][ni]);
  }

#pragma unroll
  for (int mi = 0; mi < 4; mi++) {
#pragma unroll
    for (int ni = 0; ni < 4; ni++) {
      const int gm0 = tm + wm + mi * 16 + quad * 4;  // 4 consecutive rows (reg axis)
      const int gn = tn + wn + ni * 16 + ln;
      const float bv_ = bias[gn];
      const int hh = gn >> 6, dd = gn & 63;
      const int b0 = gm0 >> 11, t0 = gm0 & 2047;
      if (z < 2) {
        u16* p = QK + (((size_t)(b0 * Hn + hh) * Tdim) + t0) * HD + dd;
#pragma unroll
        for (int r = 0; r < 4; r++) p[r * HD] = f2bf(acc[mi][ni][r] + bv_);
      } else {
        U16x4 pk;
        pk.x = f2bf(acc[mi][ni][0] + bv_);
        pk.y = f2bf(acc[mi][ni][1] + bv_);
        pk.z = f2bf(acc[mi][ni][2] + bv_);
        pk.w = f2bf(acc[mi][ni][3] + bv_);
        *(U16x4*)&Vt[((size_t)(b0 * Hn + hh) * HD + dd) * Tdim + t0] = pk;
      }
    }
  }
}

// ---------------- flash attention v3 (causal + ALiBi) ----------------
// grid: (T/64, B*H); block 256 (4 waves), wave = 16 q-rows.
// Heavy-first dispatch; static per-row softmax shift (no max reduction / rescale);
// register-prefetch K/V pipeline; l reduced once at epilogue.
#define KSTR 68
#define VSTR 132
__global__ __launch_bounds__(256, 3) void attn_k(
    const u16* __restrict__ Q, const u16* __restrict__ K, const u16* __restrict__ Vt,
    u16* __restrict__ O) {
  __shared__ alignas(16) u16 Klds[128 * KSTR];  // 17408 B
  __shared__ alignas(16) u16 Vtlds[64 * VSTR];  // 16896 B
  __shared__ alignas(16) u16 Plds[64 * VSTR];   // 16896 B (4 waves x 16 x 128 @ stride 132)

  const int qt = (int)gridDim.x - 1 - (int)blockIdx.x;  // heavy tiles first
  const int bh = blockIdx.y;
  const int b = bh >> 4, h = bh & 15;
  const int q0 = qt * 64;
  const int tid = threadIdx.x;
  const int w = tid >> 6, lane = tid & 63, ln = lane & 15, quad = lane >> 4;

  const u16* Qh = Q + (size_t)bh * Tdim * HD;
  const u16* Kh = K + (size_t)bh * Tdim * HD;
  const u16* Vh = Vt + (size_t)bh * HD * Tdim;
  const float slope = exp2f(-0.5f * (float)(h + 1));

  // Q fragments directly from global (once per block)
  bf16x8 qf[2];
  {
    const u16* qrow = Qh + (size_t)(q0 + w * 16 + ln) * HD + quad * 8;
    qf[0] = *(const bf16x8*)qrow;
    qf[1] = *(const bf16x8*)(qrow + 32);
  }
  const int qg = q0 + w * 16 + quad * 4;  // + r
  float rowterm[4];
#pragma unroll
  for (int r = 0; r < 4; r++) rowterm[r] = slope * (float)(qg + r) + 3.0f;

  float lsum[4] = {0.f, 0.f, 0.f, 0.f};
  f32x4 oacc[4] = {};
  u16* Pw = &Plds[w * 16 * VSTR];
  const int nkt = (qt >> 1) + 1;

  // prefetch tile 0 into registers
  bf16x8 kreg[4], vreg[4];
#pragma unroll
  for (int c = 0; c < 4; c++) {
    const int e = c * 2048 + tid * 8;
    kreg[c] = *(const bf16x8*)&Kh[(size_t)(e >> 6) * HD + (e & 63)];
    vreg[c] = *(const bf16x8*)&Vh[(size_t)(e >> 7) * Tdim + (e & 127)];
  }

  for (int kt = 0; kt < nkt; kt++) {
    const int kb = kt * 128;
    __syncthreads();  // previous iteration's LDS reads done
#pragma unroll
    for (int c = 0; c < 4; c++) {
      const int e = c * 2048 + tid * 8;
      *(bf16x8*)&Klds[(e >> 6) * KSTR + (e & 63)] = kreg[c];
      *(bf16x8*)&Vtlds[(e >> 7) * VSTR + (e & 127)] = vreg[c];
    }
    __syncthreads();  // staging visible

    // prefetch next tile (latency overlaps compute below)
    if (kt + 1 < nkt) {
      const int kb2 = kb + 128;
#pragma unroll
      for (int c = 0; c < 4; c++) {
        const int e = c * 2048 + tid * 8;
        kreg[c] = *(const bf16x8*)&Kh[(size_t)(kb2 + (e >> 6)) * HD + (e & 63)];
        vreg[c] = *(const bf16x8*)&Vh[(size_t)(e >> 7) * Tdim + kb2 + (e & 127)];
      }
    }

    // S = Q K^T  (wave: 16q x 128k)
    f32x4 s[8] = {};
#pragma unroll
    for (int ks = 0; ks < 2; ks++) {
#pragma unroll
      for (int ni = 0; ni < 8; ni++) {
        bf16x8 kf = *(const bf16x8*)&Klds[(ni * 16 + ln) * KSTR + ks * 32 + quad * 8];
        s[ni] = mfma16(qf[ks], kf, s[ni]);
      }
    }

    // p = exp(s/8 + slope*(j - t) - 3); static shift, exact softmax after /l
    const bool diag = (kt == nkt - 1);
#pragma unroll
    for (int ni = 0; ni < 8; ni++) {
      const int n = kb + ni * 16 + ln;
      const float sn = slope * (float)n;
#pragma unroll
      for (int r = 0; r < 4; r++) {
        float p = __expf(s[ni][r] * 0.125f + (sn - rowterm[r]));
        if (diag && n > qg + r) p = 0.f;
        lsum[r] += p;
        Pw[(quad * 4 + r) * VSTR + ni * 16 + ln] = f2bf(p);
      }
    }

    // O += P * V  (P wave-private: no barrier, lgkm waits suffice)
#pragma unroll
    for (int ks = 0; ks < 4; ks++) {
      bf16x8 pf = *(const bf16x8*)&Pw[ln * VSTR + ks * 32 + quad * 8];
#pragma unroll
      for (int nd = 0; nd < 4; nd++) {
        bf16x8 vf = *(const bf16x8*)&Vtlds[(nd * 16 + ln) * VSTR + ks * 32 + quad * 8];
        oacc[nd] = mfma16(pf, vf, oacc[nd]);
      }
    }
  }

  // reduce l across the 16 lanes holding each row (once, not per iter)
#pragma unroll
  for (int r = 0; r < 4; r++) {
#pragma unroll
    for (int off = 8; off >= 1; off >>= 1)
      lsum[r] += __shfl_xor(lsum[r], off);
  }

  // epilogue: write (b, t, h*64+d) bf16 intermediate
#pragma unroll
  for (int nd = 0; nd < 4; nd++) {
    const int d = nd * 16 + ln;
#pragma unroll
    for (int r = 0; r < 4; r++)
      O[((size_t)(b * Tdim + qg + r)) * Ddim + h * HD + d] = f2bf(oacc[nd][r] / lsum[r]);
  }
}

// ---------------- output projection GEMM (global_load_lds staging, f32 out) ----------------
__global__ __launch_bounds__(256, 2) void gemm_out(
    const u16* __restrict__ A, const u16* __restrict__ WoT, const float* __restrict__ bo,
    float* __restrict__ C) {
  __shared__ alignas(16) u16 Alds[128 * 32];
  __shared__ alignas(16) u16 Blds[128 * 32];
  const int tid = threadIdx.x;
  const int w = tid >> 6, lane = tid & 63, ln = lane & 15, quad = lane >> 4;
  const int wm = (w >> 1) * 64, wn = (w & 1) * 64;
  const int tm = blockIdx.x * 128, tn = blockIdx.y * 128;

  f32x4 acc[4][4] = {};

  const int srow = tid >> 2, scol = (tid & 3) * 8;
  const u16* ag = A + (size_t)(tm + srow) * Ddim + scol;
  const u16* ag2 = ag + (size_t)64 * Ddim;
  const u16* bg = WoT + (size_t)(tn + srow) * Ddim + scol;
  const u16* bg2 = bg + (size_t)64 * Ddim;
  u16* al = &Alds[w * 512];
  u16* al2 = &Alds[2048 + w * 512];
  u16* bl = &Blds[w * 512];
  u16* bl2 = &Blds[2048 + w * 512];

  for (int k0 = 0; k0 < Ddim; k0 += 32) {
    __syncthreads();
    cp16(ag + k0, al);
    cp16(ag2 + k0, al2);
    cp16(bg + k0, bl);
    cp16(bg2 + k0, bl2);
    __syncthreads();
    bf16x8 af[4], bfr[4];
#pragma unroll
    for (int i = 0; i < 4; i++)
      af[i] = *(const bf16x8*)&Alds[(wm + i * 16 + ln) * 32 + quad * 8];
#pragma unroll
    for (int i = 0; i < 4; i++)
      bfr[i] = *(const bf16x8*)&Blds[(wn + i * 16 + ln) * 32 + quad * 8];
#pragma unroll
    for (int mi = 0; mi < 4; mi++)
#pragma unroll
      for (int ni = 0; ni < 4; ni++)
        acc[mi][ni] = mfma16(af[mi], bfr[ni], acc[mi][ni]);
  }

#pragma unroll
  for (int mi = 0; mi < 4; mi++) {
#pragma unroll
    for (int ni = 0; ni < 4; ni++) {
      const int gm0 = tm + wm + mi * 16 + quad * 4;
      const int gn = tn + wn + ni * 16 + ln;
      const float bv_ = bo[gn];
#pragma unroll
      for (int r = 0; r < 4; r++)
        C[(size_t)(gm0 + r) * Ddim + gn] = acc[mi][ni][r] + bv_;
    }
  }
}

extern "C" void kernel_launch(void* const* d_in, const int* in_sizes, int n_in,
                              void* d_out, int out_size, void* d_ws, size_t ws_size,
                              hipStream_t stream) {
  (void)in_sizes; (void)n_in; (void)out_size; (void)ws_size;
  const float* x  = (const float*)d_in[0];
  const float* Wq = (const float*)d_in[1];
  const float* bq = (const float*)d_in[2];
  const float* Wk = (const float*)d_in[3];
  const float* bk = (const float*)d_in[4];
  const float* Wv = (const float*)d_in[5];
  const float* bv = (const float*)d_in[6];
  const float* Wo = (const float*)d_in[7];
  const float* bo = (const float*)d_in[8];

  char* ws = (char*)d_ws;
  const size_t MB = 1024 * 1024;
  u16* WqT = (u16*)(ws + 0 * MB);   // 2MB bf16 1024x1024
  u16* WkT = (u16*)(ws + 2 * MB);
  u16* WvT = (u16*)(ws + 4 * MB);
  u16* WoT = (u16*)(ws + 6 * MB);
  u16* Qb  = (u16*)(ws + 8 * MB);   // 8MB bf16 (B,H,T,64)
  u16* Kb  = (u16*)(ws + 16 * MB);
  u16* Vtb = (u16*)(ws + 24 * MB);  // 8MB bf16 (B,H,64,T)
  u16* Xb  = (u16*)(ws + 32 * MB);  // 8MB bf16 X; overlaps AO (AO written after Xb consumed)
  u16* AO  = (u16*)(ws + 32 * MB);  // 8MB bf16 (B,T,D)

  convert_x<<<dim3(2048), 256, 0, stream>>>(x, Xb);
  dim3 tb(32, 8);
  transpose_k<<<dim3(32, 32), tb, 0, stream>>>(Wq, WqT);
  transpose_k<<<dim3(32, 32), tb, 0, stream>>>(Wk, WkT);
  transpose_k<<<dim3(32, 32), tb, 0, stream>>>(Wv, WvT);
  transpose_k<<<dim3(32, 32), tb, 0, stream>>>(Wo, WoT);

  gemm_qkv<<<dim3(32, 8, 3), 256, 0, stream>>>(Xb, WqT, WkT, WvT, bq, bk, bv, Qb, Kb, Vtb);
  attn_k<<<dim3(32, 32), 256, 0, stream>>>(Qb, Kb, Vtb, AO);
  gemm_out<<<dim3(32, 8), 256, 0, stream>>>(AO, WoT, bo, (float*)d_out);
}

// Round 7
// 219.247 us; speedup vs baseline: 1.3114x; 1.1598x over previous
//
#include <hip/hip_runtime.h>
#include <hip/hip_bf16.h>

// Problem constants
#define Bn 2
#define Tdim 2048
#define Ddim 1024
#define Hn 16
#define HD 64

typedef unsigned short u16;
typedef unsigned int u32;
typedef __attribute__((ext_vector_type(8))) __bf16 bf16x8;
typedef __attribute__((ext_vector_type(4))) float f32x4;
typedef __attribute__((ext_vector_type(16))) float f32x16;
typedef __attribute__((ext_vector_type(4))) u32 u32x4;

struct alignas(8) U16x4 { u16 x, y, z, w; };

__device__ __forceinline__ u16 f2bf(float f) {
  union { float f; u32 i; } v; v.f = f;
  u32 x = v.i;
  u32 r = (x + 0x7fffu + ((x >> 16) & 1u)) >> 16;
  return (u16)r;
}
__device__ __forceinline__ u32 pk2bf(float a, float b) {
  return (u32)f2bf(a) | ((u32)f2bf(b) << 16);
}

// async global->LDS, 16B per lane; LDS dest = wave-uniform base + lane*16
__device__ __forceinline__ void cp16(const u16* g, u16* l) {
  __builtin_amdgcn_global_load_lds(
      (const __attribute__((address_space(1))) u32*)g,
      (__attribute__((address_space(3))) u32*)l, 16, 0, 0);
}

__device__ __forceinline__ f32x4 mfma16(bf16x8 a, bf16x8 b, f32x4 c) {
  return __builtin_amdgcn_mfma_f32_16x16x32_bf16(a, b, c, 0, 0, 0);
}
__device__ __forceinline__ f32x16 mfma32(bf16x8 a, bf16x8 b, f32x16 c) {
  return __builtin_amdgcn_mfma_f32_32x32x16_bf16(a, b, c, 0, 0, 0);
}

// ---------------- X f32 -> bf16 convert ----------------
__global__ __launch_bounds__(256) void convert_x(const float* __restrict__ src,
                                                 u16* __restrict__ dst) {
  const int i = (blockIdx.x * 256 + threadIdx.x) * 8;
  u16 t[8];
#pragma unroll
  for (int j = 0; j < 8; j++) t[j] = f2bf(src[i + j]);
  *(bf16x8*)&dst[i] = *(const bf16x8*)t;
}

// ---------------- weight transpose + f32->bf16 convert (4x 1024x1024, fused) ----------------
__global__ __launch_bounds__(256) void transpose_k(
    const float* __restrict__ s0, const float* __restrict__ s1,
    const float* __restrict__ s2, const float* __restrict__ s3,
    u16* __restrict__ dst) {
  const float* src = (blockIdx.z == 0) ? s0 : (blockIdx.z == 1) ? s1
                   : (blockIdx.z == 2) ? s2 : s3;
  u16* d = dst + (size_t)blockIdx.z * Ddim * Ddim;
  __shared__ u16 tile[32][33];
  const int tx = threadIdx.x, ty = threadIdx.y;
  const int x = blockIdx.x * 32 + tx;
  const int y0 = blockIdx.y * 32;
#pragma unroll
  for (int j = 0; j < 32; j += 8) tile[ty + j][tx] = f2bf(src[(size_t)(y0 + ty + j) * Ddim + x]);
  __syncthreads();
  const int xo = blockIdx.y * 32 + tx;
  const int yo0 = blockIdx.x * 32;
#pragma unroll
  for (int j = 0; j < 32; j += 8) d[(size_t)(yo0 + ty + j) * Ddim + xo] = tile[tx][ty + j];
}

// ---------------- fused QKV projection GEMM (global_load_lds staging) ----------------
__global__ __launch_bounds__(256, 2) void gemm_qkv(
    const u16* __restrict__ Xb, const u16* __restrict__ WT,
    const float* __restrict__ bq, const float* __restrict__ bk, const float* __restrict__ bv,
    u16* __restrict__ Q, u16* __restrict__ K, u16* __restrict__ Vt) {
  const int z = blockIdx.z;
  const u16* Wt = WT + (size_t)z * Ddim * Ddim;
  const float* bias = (z == 0) ? bq : (z == 1) ? bk : bv;
  u16* QK = (z == 0) ? Q : K;

  __shared__ alignas(16) u16 Alds[128 * 32];
  __shared__ alignas(16) u16 Blds[128 * 32];
  const int tid = threadIdx.x;
  const int w = tid >> 6, lane = tid & 63, ln = lane & 15, quad = lane >> 4;
  const int wm = (w >> 1) * 64, wn = (w & 1) * 64;
  const int tm = blockIdx.x * 128, tn = blockIdx.y * 128;

  f32x4 acc[4][4] = {};

  const int srow = tid >> 2, scol = (tid & 3) * 8;
  const u16* ag = Xb + (size_t)(tm + srow) * Ddim + scol;
  const u16* ag2 = ag + (size_t)64 * Ddim;
  const u16* bg = Wt + (size_t)(tn + srow) * Ddim + scol;
  const u16* bg2 = bg + (size_t)64 * Ddim;
  u16* al = &Alds[w * 512];
  u16* al2 = &Alds[2048 + w * 512];
  u16* bl = &Blds[w * 512];
  u16* bl2 = &Blds[2048 + w * 512];

  for (int k0 = 0; k0 < Ddim; k0 += 32) {
    __syncthreads();
    cp16(ag + k0, al);
    cp16(ag2 + k0, al2);
    cp16(bg + k0, bl);
    cp16(bg2 + k0, bl2);
    __syncthreads();
    bf16x8 af[4], bfr[4];
#pragma unroll
    for (int i = 0; i < 4; i++)
      af[i] = *(const bf16x8*)&Alds[(wm + i * 16 + ln) * 32 + quad * 8];
#pragma unroll
    for (int i = 0; i < 4; i++)
      bfr[i] = *(const bf16x8*)&Blds[(wn + i * 16 + ln) * 32 + quad * 8];
#pragma unroll
    for (int mi = 0; mi < 4; mi++)
#pragma unroll
      for (int ni = 0; ni < 4; ni++)
        acc[mi][ni] = mfma16(af[mi], bfr[ni], acc[mi][ni]);
  }

#pragma unroll
  for (int mi = 0; mi < 4; mi++) {
#pragma unroll
    for (int ni = 0; ni < 4; ni++) {
      const int gm0 = tm + wm + mi * 16 + quad * 4;
      const int gn = tn + wn + ni * 16 + ln;
      const float bv_ = bias[gn];
      const int hh = gn >> 6, dd = gn & 63;
      const int b0 = gm0 >> 11, t0 = gm0 & 2047;
      if (z < 2) {
        u16* p = QK + (((size_t)(b0 * Hn + hh) * Tdim) + t0) * HD + dd;
#pragma unroll
        for (int r = 0; r < 4; r++) p[r * HD] = f2bf(acc[mi][ni][r] + bv_);
      } else {
        U16x4 pk;
        pk.x = f2bf(acc[mi][ni][0] + bv_);
        pk.y = f2bf(acc[mi][ni][1] + bv_);
        pk.z = f2bf(acc[mi][ni][2] + bv_);
        pk.w = f2bf(acc[mi][ni][3] + bv_);
        *(U16x4*)&Vt[((size_t)(b0 * Hn + hh) * HD + dd) * Tdim + t0] = pk;
      }
    }
  }
}

// ---------------- flash attention v4: 32x32 MFMA + S^T + register P-transform ----------------
// grid (16 qb, 32 bh), heavy-first. Block = 4 waves x 32 q-rows = 128 rows.
// S^T = K*Q^T so each lane owns ONE q-row (q = lane&31): scalar lsum, no P LDS.
#define KSTR 68
#define VSTR 132
__global__ __launch_bounds__(256, 2) void attn_k(
    const u16* __restrict__ Q, const u16* __restrict__ K, const u16* __restrict__ Vt,
    u16* __restrict__ O) {
  __shared__ alignas(16) u16 Klds[128 * KSTR];  // 17408 B
  __shared__ alignas(16) u16 Vtlds[64 * VSTR];  // 16896 B

  const int qb = (int)gridDim.x - 1 - (int)blockIdx.x;  // heavy first
  const int bh = blockIdx.y;
  const int b = bh >> 4, hh = bh & 15;
  const int q0 = qb * 128;
  const int tid = threadIdx.x;
  const int w = tid >> 6, lane = tid & 63;
  const int qi = lane & 31, hf = lane >> 5;  // q-in-wave, half

  const u16* Qh = Q + (size_t)bh * Tdim * HD;
  const u16* Kh = K + (size_t)bh * Tdim * HD;
  const u16* Vh = Vt + (size_t)bh * HD * Tdim;
  const float slope = exp2f(-0.5f * (float)(hh + 1));

  const int tg = q0 + w * 32 + qi;             // this lane's q-row (global)
  const float tterm = slope * (float)tg + 3.0f;

  // Q fragments (B-operand): lane holds row qi, hd chunk kc*16 + hf*8
  bf16x8 qf[4];
#pragma unroll
  for (int kc = 0; kc < 4; kc++)
    qf[kc] = *(const bf16x8*)&Qh[(size_t)tg * HD + kc * 16 + hf * 8];

  float lsum = 0.f;
  f32x16 oacc[2] = {};
  const int nkt = qb + 1;

  // prefetch tile 0
  bf16x8 kreg[4], vreg[4];
#pragma unroll
  for (int c = 0; c < 4; c++) {
    const int e = c * 2048 + tid * 8;
    kreg[c] = *(const bf16x8*)&Kh[(size_t)(e >> 6) * HD + (e & 63)];
    vreg[c] = *(const bf16x8*)&Vh[(size_t)(e >> 7) * Tdim + (e & 127)];
  }

  for (int kt = 0; kt < nkt; kt++) {
    const int kb = kt * 128;
    __syncthreads();
#pragma unroll
    for (int c = 0; c < 4; c++) {
      const int e = c * 2048 + tid * 8;
      *(bf16x8*)&Klds[(e >> 6) * KSTR + (e & 63)] = kreg[c];
      *(bf16x8*)&Vtlds[(e >> 7) * VSTR + (e & 127)] = vreg[c];
    }
    __syncthreads();

    if (kt + 1 < nkt) {
      const int kb2 = kb + 128;
#pragma unroll
      for (int c = 0; c < 4; c++) {
        const int e = c * 2048 + tid * 8;
        kreg[c] = *(const bf16x8*)&Kh[(size_t)(kb2 + (e >> 6)) * HD + (e & 63)];
        vreg[c] = *(const bf16x8*)&Vh[(size_t)(e >> 7) * Tdim + kb2 + (e & 127)];
      }
    }

    // S^T = K Q^T : per tile ni (32 keys), A = K-frag, B = Q-frag
    f32x16 st[4] = {};
#pragma unroll
    for (int kc = 0; kc < 4; kc++) {
#pragma unroll
      for (int ni = 0; ni < 4; ni++) {
        bf16x8 kf = *(const bf16x8*)&Klds[(ni * 32 + qi) * KSTR + kc * 16 + hf * 8];
        st[ni] = mfma32(kf, qf[kc], st[ni]);
      }
    }

    // exp + mask + pack + cross-half exchange -> P A-fragments
    const bool diag = (kt == nkt - 1);
    bf16x8 pfrag[8];
#pragma unroll
    for (int ni = 0; ni < 4; ni++) {
      float p[16];
#pragma unroll
      for (int ri = 0; ri < 16; ri++) {
        const int n = kb + ni * 32 + (ri & 3) + 8 * (ri >> 2) + 4 * hf;
        float pv = __expf(st[ni][ri] * 0.125f + slope * (float)n - tterm);
        if (diag && n > tg) pv = 0.f;
        lsum += pv;
        p[ri] = pv;
      }
      u32 pk[4][2];
#pragma unroll
      for (int g = 0; g < 4; g++) {
        pk[g][0] = pk2bf(p[g * 4 + 0], p[g * 4 + 1]);
        pk[g][1] = pk2bf(p[g * 4 + 2], p[g * 4 + 3]);
      }
      // A-frag kf16 = ni*2 + a needs reg-group (2a + hf) from BOTH halves.
#pragma unroll
      for (int a = 0; a < 2; a++) {
        const u32 own0 = (hf == 0) ? pk[2 * a][0] : pk[2 * a + 1][0];
        const u32 own1 = (hf == 0) ? pk[2 * a][1] : pk[2 * a + 1][1];
        const u32 snd0 = (hf == 0) ? pk[2 * a + 1][0] : pk[2 * a][0];
        const u32 snd1 = (hf == 0) ? pk[2 * a + 1][1] : pk[2 * a][1];
        const u32 rcv0 = (u32)__shfl_xor((int)snd0, 32);
        const u32 rcv1 = (u32)__shfl_xor((int)snd1, 32);
        u32x4 fr;
        fr.x = (hf == 0) ? own0 : rcv0;
        fr.y = (hf == 0) ? own1 : rcv1;
        fr.z = (hf == 0) ? rcv0 : own0;
        fr.w = (hf == 0) ? rcv1 : own1;
        pfrag[ni * 2 + a] = *(bf16x8*)&fr;
      }
    }

    // O += P * V  (B = V^T rows)
#pragma unroll
    for (int kf16 = 0; kf16 < 8; kf16++) {
#pragma unroll
      for (int nd = 0; nd < 2; nd++) {
        bf16x8 vf = *(const bf16x8*)&Vtlds[(nd * 32 + qi) * VSTR + kf16 * 16 + hf * 8];
        oacc[nd] = mfma32(pfrag[kf16], vf, oacc[nd]);
      }
    }
  }

  // l: combine halves (each lane then holds full l for q = qi)
  lsum += __shfl_xor(lsum, 32);

  // per-reg row l broadcast + write O (row = (ri&3)+8*(ri>>2)+4*hf)
  float rinv[16];
#pragma unroll
  for (int ri = 0; ri < 16; ri++) {
    const int rq = (ri & 3) + 8 * (ri >> 2) + 4 * hf;
    rinv[ri] = 1.0f / __shfl(lsum, rq);
  }
#pragma unroll
  for (int nd = 0; nd < 2; nd++) {
#pragma unroll
    for (int ri = 0; ri < 16; ri++) {
      const int rq = (ri & 3) + 8 * (ri >> 2) + 4 * hf;
      const int t = q0 + w * 32 + rq;
      O[((size_t)(b * Tdim + t)) * Ddim + hh * HD + nd * 32 + qi] =
          f2bf(oacc[nd][ri] * rinv[ri]);
    }
  }
}

// ---------------- output projection GEMM (f32 out) ----------------
__global__ __launch_bounds__(256, 2) void gemm_out(
    const u16* __restrict__ A, const u16* __restrict__ WoT, const float* __restrict__ bo,
    float* __restrict__ C) {
  __shared__ alignas(16) u16 Alds[128 * 32];
  __shared__ alignas(16) u16 Blds[128 * 32];
  const int tid = threadIdx.x;
  const int w = tid >> 6, lane = tid & 63, ln = lane & 15, quad = lane >> 4;
  const int wm = (w >> 1) * 64, wn = (w & 1) * 64;
  const int tm = blockIdx.x * 128, tn = blockIdx.y * 128;

  f32x4 acc[4][4] = {};

  const int srow = tid >> 2, scol = (tid & 3) * 8;
  const u16* ag = A + (size_t)(tm + srow) * Ddim + scol;
  const u16* ag2 = ag + (size_t)64 * Ddim;
  const u16* bg = WoT + (size_t)(tn + srow) * Ddim + scol;
  const u16* bg2 = bg + (size_t)64 * Ddim;
  u16* al = &Alds[w * 512];
  u16* al2 = &Alds[2048 + w * 512];
  u16* bl = &Blds[w * 512];
  u16* bl2 = &Blds[2048 + w * 512];

  for (int k0 = 0; k0 < Ddim; k0 += 32) {
    __syncthreads();
    cp16(ag + k0, al);
    cp16(ag2 + k0, al2);
    cp16(bg + k0, bl);
    cp16(bg2 + k0, bl2);
    __syncthreads();
    bf16x8 af[4], bfr[4];
#pragma unroll
    for (int i = 0; i < 4; i++)
      af[i] = *(const bf16x8*)&Alds[(wm + i * 16 + ln) * 32 + quad * 8];
#pragma unroll
    for (int i = 0; i < 4; i++)
      bfr[i] = *(const bf16x8*)&Blds[(wn + i * 16 + ln) * 32 + quad * 8];
#pragma unroll
    for (int mi = 0; mi < 4; mi++)
#pragma unroll
      for (int ni = 0; ni < 4; ni++)
        acc[mi][ni] = mfma16(af[mi], bfr[ni], acc[mi][ni]);
  }

#pragma unroll
  for (int mi = 0; mi < 4; mi++) {
#pragma unroll
    for (int ni = 0; ni < 4; ni++) {
      const int gm0 = tm + wm + mi * 16 + quad * 4;
      const int gn = tn + wn + ni * 16 + ln;
      const float bv_ = bo[gn];
#pragma unroll
      for (int r = 0; r < 4; r++)
        C[(size_t)(gm0 + r) * Ddim + gn] = acc[mi][ni][r] + bv_;
    }
  }
}

extern "C" void kernel_launch(void* const* d_in, const int* in_sizes, int n_in,
                              void* d_out, int out_size, void* d_ws, size_t ws_size,
                              hipStream_t stream) {
  (void)in_sizes; (void)n_in; (void)out_size; (void)ws_size;
  const float* x  = (const float*)d_in[0];
  const float* Wq = (const float*)d_in[1];
  const float* bq = (const float*)d_in[2];
  const float* Wk = (const float*)d_in[3];
  const float* bk = (const float*)d_in[4];
  const float* Wv = (const float*)d_in[5];
  const float* bv = (const float*)d_in[6];
  const float* Wo = (const float*)d_in[7];
  const float* bo = (const float*)d_in[8];

  char* ws = (char*)d_ws;
  const size_t MB = 1024 * 1024;
  u16* WT  = (u16*)(ws + 0 * MB);   // 8MB: WqT, WkT, WvT, WoT (z-major)
  u16* Qb  = (u16*)(ws + 8 * MB);   // 8MB bf16 (B,H,T,64)
  u16* Kb  = (u16*)(ws + 16 * MB);
  u16* Vtb = (u16*)(ws + 24 * MB);  // 8MB bf16 (B,H,64,T)
  u16* Xb  = (u16*)(ws + 32 * MB);  // 8MB bf16 X; overlaps AO
  u16* AO  = (u16*)(ws + 32 * MB);  // 8MB bf16 (B,T,D)
  u16* WoT = WT + (size_t)3 * Ddim * Ddim;

  convert_x<<<dim3(2048), 256, 0, stream>>>(x, Xb);
  transpose_k<<<dim3(32, 32, 4), dim3(32, 8), 0, stream>>>(Wq, Wk, Wv, Wo, WT);

  gemm_qkv<<<dim3(32, 8, 3), 256, 0, stream>>>(Xb, WT, bq, bk, bv, Qb, Kb, Vtb);
  attn_k<<<dim3(16, 32), 256, 0, stream>>>(Qb, Kb, Vtb, AO);
  gemm_out<<<dim3(32, 8), 256, 0, stream>>>(AO, WoT, bo, (float*)d_out);
}

// Round 8
// 204.780 us; speedup vs baseline: 1.4040x; 1.0706x over previous
//
#include <hip/hip_runtime.h>
#include <hip/hip_bf16.h>

// Problem constants
#define Bn 2
#define Tdim 2048
#define Ddim 1024
#define Hn 16
#define HD 64

typedef unsigned short u16;
typedef unsigned int u32;
typedef __attribute__((ext_vector_type(8))) __bf16 bf16x8;
typedef __attribute__((ext_vector_type(4))) float f32x4;
typedef __attribute__((ext_vector_type(16))) float f32x16;
typedef __attribute__((ext_vector_type(4))) u32 u32x4;

struct alignas(8) U16x4 { u16 x, y, z, w; };

__device__ __forceinline__ u16 f2bf(float f) {
  union { float f; u32 i; } v; v.f = f;
  u32 x = v.i;
  u32 r = (x + 0x7fffu + ((x >> 16) & 1u)) >> 16;
  return (u16)r;
}
__device__ __forceinline__ float bf2f(u16 u) {
  union { u32 i; float f; } v; v.i = ((u32)u) << 16; return v.f;
}
__device__ __forceinline__ u32 fbits(float f) {
  union { float f; u32 i; } v; v.f = f; return v.i;
}

// async global->LDS, 16B per lane; LDS dest = wave-uniform base + lane*16
__device__ __forceinline__ void cp16(const u16* g, u16* l) {
  __builtin_amdgcn_global_load_lds(
      (const __attribute__((address_space(1))) u32*)g,
      (__attribute__((address_space(3))) u32*)l, 16, 0, 0);
}

__device__ __forceinline__ f32x4 mfma16(bf16x8 a, bf16x8 b, f32x4 c) {
  return __builtin_amdgcn_mfma_f32_16x16x32_bf16(a, b, c, 0, 0, 0);
}
__device__ __forceinline__ f32x16 mfma32(bf16x8 a, bf16x8 b, f32x16 c) {
  return __builtin_amdgcn_mfma_f32_32x32x16_bf16(a, b, c, 0, 0, 0);
}

// ---------------- X f32 -> bf16 convert ----------------
__global__ __launch_bounds__(256) void convert_x(const float* __restrict__ src,
                                                 u16* __restrict__ dst) {
  const int i = (blockIdx.x * 256 + threadIdx.x) * 8;
  u16 t[8];
#pragma unroll
  for (int j = 0; j < 8; j++) t[j] = f2bf(src[i + j]);
  *(bf16x8*)&dst[i] = *(const bf16x8*)t;
}

// ---------------- weight transpose + f32->bf16 convert (4x 1024x1024, fused) ----------------
__global__ __launch_bounds__(256) void transpose_k(
    const float* __restrict__ s0, const float* __restrict__ s1,
    const float* __restrict__ s2, const float* __restrict__ s3,
    u16* __restrict__ dst) {
  const float* src = (blockIdx.z == 0) ? s0 : (blockIdx.z == 1) ? s1
                   : (blockIdx.z == 2) ? s2 : s3;
  u16* d = dst + (size_t)blockIdx.z * Ddim * Ddim;
  __shared__ u16 tile[32][33];
  const int tx = threadIdx.x, ty = threadIdx.y;
  const int x = blockIdx.x * 32 + tx;
  const int y0 = blockIdx.y * 32;
#pragma unroll
  for (int j = 0; j < 32; j += 8) tile[ty + j][tx] = f2bf(src[(size_t)(y0 + ty + j) * Ddim + x]);
  __syncthreads();
  const int xo = blockIdx.y * 32 + tx;
  const int yo0 = blockIdx.x * 32;
#pragma unroll
  for (int j = 0; j < 32; j += 8) d[(size_t)(yo0 + ty + j) * Ddim + xo] = tile[tx][ty + j];
}

// ---------------- fused QKV projection GEMM (global_load_lds staging) ----------------
__global__ __launch_bounds__(256, 2) void gemm_qkv(
    const u16* __restrict__ Xb, const u16* __restrict__ WT,
    const float* __restrict__ bq, const float* __restrict__ bk, const float* __restrict__ bv,
    u16* __restrict__ Q, u16* __restrict__ K, u16* __restrict__ Vt) {
  const int z = blockIdx.z;
  const u16* Wt = WT + (size_t)z * Ddim * Ddim;
  const float* bias = (z == 0) ? bq : (z == 1) ? bk : bv;
  u16* QK = (z == 0) ? Q : K;

  __shared__ alignas(16) u16 Alds[128 * 32];
  __shared__ alignas(16) u16 Blds[128 * 32];
  const int tid = threadIdx.x;
  const int w = tid >> 6, lane = tid & 63, ln = lane & 15, quad = lane >> 4;
  const int wm = (w >> 1) * 64, wn = (w & 1) * 64;
  const int tm = blockIdx.x * 128, tn = blockIdx.y * 128;

  f32x4 acc[4][4] = {};

  const int srow = tid >> 2, scol = (tid & 3) * 8;
  const u16* ag = Xb + (size_t)(tm + srow) * Ddim + scol;
  const u16* ag2 = ag + (size_t)64 * Ddim;
  const u16* bg = Wt + (size_t)(tn + srow) * Ddim + scol;
  const u16* bg2 = bg + (size_t)64 * Ddim;
  u16* al = &Alds[w * 512];
  u16* al2 = &Alds[2048 + w * 512];
  u16* bl = &Blds[w * 512];
  u16* bl2 = &Blds[2048 + w * 512];

  for (int k0 = 0; k0 < Ddim; k0 += 32) {
    __syncthreads();
    cp16(ag + k0, al);
    cp16(ag2 + k0, al2);
    cp16(bg + k0, bl);
    cp16(bg2 + k0, bl2);
    __syncthreads();
    bf16x8 af[4], bfr[4];
#pragma unroll
    for (int i = 0; i < 4; i++)
      af[i] = *(const bf16x8*)&Alds[(wm + i * 16 + ln) * 32 + quad * 8];
#pragma unroll
    for (int i = 0; i < 4; i++)
      bfr[i] = *(const bf16x8*)&Blds[(wn + i * 16 + ln) * 32 + quad * 8];
#pragma unroll
    for (int mi = 0; mi < 4; mi++)
#pragma unroll
      for (int ni = 0; ni < 4; ni++)
        acc[mi][ni] = mfma16(af[mi], bfr[ni], acc[mi][ni]);
  }

#pragma unroll
  for (int mi = 0; mi < 4; mi++) {
#pragma unroll
    for (int ni = 0; ni < 4; ni++) {
      const int gm0 = tm + wm + mi * 16 + quad * 4;
      const int gn = tn + wn + ni * 16 + ln;
      const float bv_ = bias[gn];
      const int hh = gn >> 6, dd = gn & 63;
      const int b0 = gm0 >> 11, t0 = gm0 & 2047;
      if (z < 2) {
        u16* p = QK + (((size_t)(b0 * Hn + hh) * Tdim) + t0) * HD + dd;
#pragma unroll
        for (int r = 0; r < 4; r++) p[r * HD] = f2bf(acc[mi][ni][r] + bv_);
      } else {
        U16x4 pk;
        pk.x = f2bf(acc[mi][ni][0] + bv_);
        pk.y = f2bf(acc[mi][ni][1] + bv_);
        pk.z = f2bf(acc[mi][ni][2] + bv_);
        pk.w = f2bf(acc[mi][ni][3] + bv_);
        *(U16x4*)&Vt[((size_t)(b0 * Hn + hh) * HD + dd) * Tdim + t0] = pk;
      }
    }
  }
}

// ---------------- flash attention v5: split-K halves + lean exp2 softmax ----------------
// grid (32, 32): bx -> qb = 15-(bx>>1) (heavy first), s = bx&1 (key-range half).
// Block = 4 waves x 32 q-rows. Static-shift softmax => partials add linearly.
#define KSTR 68
#define VSTR 132
#define L2E 1.44269504088896f
__global__ __launch_bounds__(256, 2) void attn_k(
    const u16* __restrict__ Q, const u16* __restrict__ K, const u16* __restrict__ Vt,
    u16* __restrict__ Op, float* __restrict__ lp) {
  __shared__ alignas(16) u16 Klds[128 * KSTR];
  __shared__ alignas(16) u16 Vtlds[64 * VSTR];

  const int bx = blockIdx.x;
  const int qb = 15 - (bx >> 1);
  const int s = bx & 1;
  const int bh = blockIdx.y;
  const int q0 = qb * 128;
  const int tid = threadIdx.x;
  const int w = tid >> 6, lane = tid & 63;
  const int qi = lane & 31, hf = lane >> 5;

  const u16* Qh = Q + (size_t)bh * Tdim * HD;
  const u16* Kh = K + (size_t)bh * Tdim * HD;
  const u16* Vh = Vt + (size_t)bh * HD * Tdim;
  const float slope = exp2f(-0.5f * (float)((bh & 15) + 1));

  const int nkt = qb + 1;
  const int h0 = (nkt + 1) >> 1;
  const int kt0 = s ? h0 : 0;
  const int kt1 = s ? nkt : h0;

  const int tg = q0 + w * 32 + qi;  // this lane's q-row
  const float sl2 = slope * L2E;
  const float c1 = 0.125f * L2E;
  const float tt2 = (slope * (float)tg + 3.0f) * L2E;
  const float f4hf = (float)(4 * hf);
  // hoisted per-block constants for exponent folding
  float sg8[4], slm[4];
#pragma unroll
  for (int g = 0; g < 4; g++) sg8[g] = sl2 * (float)(8 * g);
#pragma unroll
  for (int m = 0; m < 4; m++) slm[m] = sl2 * (float)m;

  // Q fragments (B-operand)
  bf16x8 qf[4];
#pragma unroll
  for (int kc = 0; kc < 4; kc++)
    qf[kc] = *(const bf16x8*)&Qh[(size_t)tg * HD + kc * 16 + hf * 8];

  float lsum = 0.f;
  f32x16 oacc[2] = {};

  // prefetch first tile of this half
  bf16x8 kreg[4], vreg[4];
  {
    const int kb = kt0 * 128;
#pragma unroll
    for (int c = 0; c < 4; c++) {
      const int e = c * 2048 + tid * 8;
      kreg[c] = *(const bf16x8*)&Kh[(size_t)(kb + (e >> 6)) * HD + (e & 63)];
      vreg[c] = *(const bf16x8*)&Vh[(size_t)(e >> 7) * Tdim + kb + (e & 127)];
    }
  }

  for (int kt = kt0; kt < kt1; kt++) {
    const int kb = kt * 128;
    __syncthreads();
#pragma unroll
    for (int c = 0; c < 4; c++) {
      const int e = c * 2048 + tid * 8;
      *(bf16x8*)&Klds[(e >> 6) * KSTR + (e & 63)] = kreg[c];
      *(bf16x8*)&Vtlds[(e >> 7) * VSTR + (e & 127)] = vreg[c];
    }
    __syncthreads();

    if (kt + 1 < kt1) {
      const int kb2 = kb + 128;
#pragma unroll
      for (int c = 0; c < 4; c++) {
        const int e = c * 2048 + tid * 8;
        kreg[c] = *(const bf16x8*)&Kh[(size_t)(kb2 + (e >> 6)) * HD + (e & 63)];
        vreg[c] = *(const bf16x8*)&Vh[(size_t)(e >> 7) * Tdim + kb2 + (e & 127)];
      }
    }

    // S^T = K Q^T
    f32x16 st[4] = {};
#pragma unroll
    for (int kc = 0; kc < 4; kc++) {
#pragma unroll
      for (int ni = 0; ni < 4; ni++) {
        bf16x8 kf = *(const bf16x8*)&Klds[(ni * 32 + qi) * KSTR + kc * 16 + hf * 8];
        st[ni] = mfma32(kf, qf[kc], st[ni]);
      }
    }

    // p = exp2(st*c1 + const(ni,g,m));  E-constants folded, diag split out
    const bool diag = (kt == nkt - 1);
    const float fkb = (float)kb + f4hf;
    bf16x8 pfrag[8];
#pragma unroll
    for (int ni = 0; ni < 4; ni++) {
      const float cni = __builtin_fmaf(sl2, fkb + (float)(32 * ni), -tt2);
      u32 pu[16];
      if (!diag) {
#pragma unroll
        for (int ri = 0; ri < 16; ri++) {
          const float e = __builtin_fmaf(st[ni][ri], c1, cni + sg8[ri >> 2] + slm[ri & 3]);
          const float p = __builtin_amdgcn_exp2f(e);
          lsum += p;
          pu[ri] = fbits(p) + 0x8000u;
        }
      } else {
#pragma unroll
        for (int ri = 0; ri < 16; ri++) {
          const int n = kb + ni * 32 + (ri & 3) + 8 * (ri >> 2) + 4 * hf;
          const float e = __builtin_fmaf(st[ni][ri], c1, cni + sg8[ri >> 2] + slm[ri & 3]);
          float p = __builtin_amdgcn_exp2f(e);
          if (n > tg) p = 0.f;
          lsum += p;
          pu[ri] = fbits(p) + 0x8000u;
        }
      }
      u32 pk[4][2];
#pragma unroll
      for (int g = 0; g < 4; g++) {
        pk[g][0] = __builtin_amdgcn_perm(pu[g * 4 + 1], pu[g * 4 + 0], 0x07060302u);
        pk[g][1] = __builtin_amdgcn_perm(pu[g * 4 + 3], pu[g * 4 + 2], 0x07060302u);
      }
#pragma unroll
      for (int a = 0; a < 2; a++) {
        const u32 snd0 = (hf == 0) ? pk[2 * a + 1][0] : pk[2 * a][0];
        const u32 snd1 = (hf == 0) ? pk[2 * a + 1][1] : pk[2 * a][1];
        const u32 rcv0 = (u32)__shfl_xor((int)snd0, 32);
        const u32 rcv1 = (u32)__shfl_xor((int)snd1, 32);
        u32x4 fr;
        fr.x = (hf == 0) ? pk[2 * a][0] : rcv0;
        fr.y = (hf == 0) ? pk[2 * a][1] : rcv1;
        fr.z = (hf == 0) ? rcv0 : pk[2 * a + 1][0];
        fr.w = (hf == 0) ? rcv1 : pk[2 * a + 1][1];
        pfrag[ni * 2 + a] = *(bf16x8*)&fr;
      }
    }

    // O += P * V
#pragma unroll
    for (int kf16 = 0; kf16 < 8; kf16++) {
#pragma unroll
      for (int nd = 0; nd < 2; nd++) {
        bf16x8 vf = *(const bf16x8*)&Vtlds[(nd * 32 + qi) * VSTR + kf16 * 16 + hf * 8];
        oacc[nd] = mfma32(pfrag[kf16], vf, oacc[nd]);
      }
    }
  }

  // combine key-halves of l within wave; write partials (no normalize)
  lsum += __shfl_xor(lsum, 32);
  if (hf == 0) lp[(size_t)s * 65536 + bh * Tdim + tg] = lsum;

  u16* Ob = Op + (size_t)s * (32u * Tdim * HD) + ((size_t)bh * Tdim) * HD;
#pragma unroll
  for (int nd = 0; nd < 2; nd++) {
#pragma unroll
    for (int ri = 0; ri < 16; ri++) {
      const int rq = (ri & 3) + 8 * (ri >> 2) + 4 * hf;
      const int t = q0 + w * 32 + rq;
      Ob[(size_t)t * HD + nd * 32 + qi] = f2bf(oacc[nd][ri]);
    }
  }
}

// ---------------- merge partials + normalize -> AO bf16 ----------------
__global__ __launch_bounds__(256) void merge_k(const u16* __restrict__ Op,
                                               const float* __restrict__ lp,
                                               u16* __restrict__ AO) {
  const int i = blockIdx.x * 256 + threadIdx.x;  // octet index
  const int d8 = i & 7;
  const int t = (i >> 3) & 2047;
  const int bh = i >> 14;
  const int b = bh >> 4, h = bh & 15;
  const float l = lp[bh * Tdim + t] + lp[65536 + bh * Tdim + t];
  const float inv = 1.0f / l;
  const size_t off = ((size_t)bh * Tdim + t) * HD + d8 * 8;
  const u16* O0 = Op + off;
  const u16* O1 = Op + (size_t)32 * Tdim * HD + off;
  u16 outv[8];
#pragma unroll
  for (int j = 0; j < 8; j++)
    outv[j] = f2bf((bf2f(O0[j]) + bf2f(O1[j])) * inv);
  *(bf16x8*)&AO[((size_t)(b * Tdim + t)) * Ddim + h * HD + d8 * 8] = *(const bf16x8*)outv;
}

// ---------------- output projection GEMM (f32 out) ----------------
__global__ __launch_bounds__(256, 2) void gemm_out(
    const u16* __restrict__ A, const u16* __restrict__ WoT, const float* __restrict__ bo,
    float* __restrict__ C) {
  __shared__ alignas(16) u16 Alds[128 * 32];
  __shared__ alignas(16) u16 Blds[128 * 32];
  const int tid = threadIdx.x;
  const int w = tid >> 6, lane = tid & 63, ln = lane & 15, quad = lane >> 4;
  const int wm = (w >> 1) * 64, wn = (w & 1) * 64;
  const int tm = blockIdx.x * 128, tn = blockIdx.y * 128;

  f32x4 acc[4][4] = {};

  const int srow = tid >> 2, scol = (tid & 3) * 8;
  const u16* ag = A + (size_t)(tm + srow) * Ddim + scol;
  const u16* ag2 = ag + (size_t)64 * Ddim;
  const u16* bg = WoT + (size_t)(tn + srow) * Ddim + scol;
  const u16* bg2 = bg + (size_t)64 * Ddim;
  u16* al = &Alds[w * 512];
  u16* al2 = &Alds[2048 + w * 512];
  u16* bl = &Blds[w * 512];
  u16* bl2 = &Blds[2048 + w * 512];

  for (int k0 = 0; k0 < Ddim; k0 += 32) {
    __syncthreads();
    cp16(ag + k0, al);
    cp16(ag2 + k0, al2);
    cp16(bg + k0, bl);
    cp16(bg2 + k0, bl2);
    __syncthreads();
    bf16x8 af[4], bfr[4];
#pragma unroll
    for (int i = 0; i < 4; i++)
      af[i] = *(const bf16x8*)&Alds[(wm + i * 16 + ln) * 32 + quad * 8];
#pragma unroll
    for (int i = 0; i < 4; i++)
      bfr[i] = *(const bf16x8*)&Blds[(wn + i * 16 + ln) * 32 + quad * 8];
#pragma unroll
    for (int mi = 0; mi < 4; mi++)
#pragma unroll
      for (int ni = 0; ni < 4; ni++)
        acc[mi][ni] = mfma16(af[mi], bfr[ni], acc[mi][ni]);
  }

#pragma unroll
  for (int mi = 0; mi < 4; mi++) {
#pragma unroll
    for (int ni = 0; ni < 4; ni++) {
      const int gm0 = tm + wm + mi * 16 + quad * 4;
      const int gn = tn + wn + ni * 16 + ln;
      const float bv_ = bo[gn];
#pragma unroll
      for (int r = 0; r < 4; r++)
        C[(size_t)(gm0 + r) * Ddim + gn] = acc[mi][ni][r] + bv_;
    }
  }
}

extern "C" void kernel_launch(void* const* d_in, const int* in_sizes, int n_in,
                              void* d_out, int out_size, void* d_ws, size_t ws_size,
                              hipStream_t stream) {
  (void)in_sizes; (void)n_in; (void)out_size; (void)ws_size;
  const float* x  = (const float*)d_in[0];
  const float* Wq = (const float*)d_in[1];
  const float* bq = (const float*)d_in[2];
  const float* Wk = (const float*)d_in[3];
  const float* bk = (const float*)d_in[4];
  const float* Wv = (const float*)d_in[5];
  const float* bv = (const float*)d_in[6];
  const float* Wo = (const float*)d_in[7];
  const float* bo = (const float*)d_in[8];

  char* ws = (char*)d_ws;
  const size_t MB = 1024 * 1024;
  u16* WT   = (u16*)(ws + 0 * MB);   // 8MB: WqT, WkT, WvT, WoT (z-major)
  u16* Qb   = (u16*)(ws + 8 * MB);   // 8MB bf16 (B,H,T,64)
  u16* Kb   = (u16*)(ws + 16 * MB);
  u16* Vtb  = (u16*)(ws + 24 * MB);  // 8MB bf16 (B,H,64,T)
  u16* Xb   = (u16*)(ws + 32 * MB);  // 8MB bf16 X; overlaps AO
  u16* AO   = (u16*)(ws + 32 * MB);  // 8MB bf16 (B,T,D)
  u16* Opart= (u16*)(ws + 40 * MB);  // 16MB: 2 x (BH,T,64) bf16 partial O
  float* lpart = (float*)(ws + 56 * MB); // 512KB: 2 x (BH,T) f32 partial l
  u16* WoT = WT + (size_t)3 * Ddim * Ddim;

  convert_x<<<dim3(2048), 256, 0, stream>>>(x, Xb);
  transpose_k<<<dim3(32, 32, 4), dim3(32, 8), 0, stream>>>(Wq, Wk, Wv, Wo, WT);

  gemm_qkv<<<dim3(32, 8, 3), 256, 0, stream>>>(Xb, WT, bq, bk, bv, Qb, Kb, Vtb);
  attn_k<<<dim3(32, 32), 256, 0, stream>>>(Qb, Kb, Vtb, Opart, lpart);
  merge_k<<<dim3(2048), 256, 0, stream>>>(Opart, lpart, AO);
  gemm_out<<<dim3(32, 8), 256, 0, stream>>>(AO, WoT, bo, (float*)d_out);
}